// Round 10
// baseline (710.726 us; speedup 1.0000x reference)
//
#include <hip/hip_runtime.h>
#include <hip/hip_bf16.h>

typedef unsigned short u16;
typedef __attribute__((ext_vector_type(8))) short short8;  // 8 bf16 (4 VGPRs)
typedef __attribute__((ext_vector_type(4))) float f32x4;

#define BATCH 8
#define CH 256
#define NPIX 4096
#define KD 32   // C/8

static __device__ __forceinline__ u16 f2bf(float f) {
  union { __hip_bfloat16 h; u16 u; } cv;
  cv.h = __float2bfloat16(f);
  return cv.u;
}

static __device__ __forceinline__ float bf2f(u16 u) {
  union { unsigned int i; float f; } cv;
  cv.i = ((unsigned int)u) << 16;
  return cv.f;
}

// ---------------------------------------------------------------------------
// Kernel 1: projections. x [B][C][N] f32 -> fT/gT [B][N][32] bf16, hh [B][C][N] bf16
// ---------------------------------------------------------------------------
__global__ __launch_bounds__(256) void proj_kernel(
    const float* __restrict__ x,
    const float* __restrict__ Wf, const float* __restrict__ bfp,
    const float* __restrict__ Wg, const float* __restrict__ bgp,
    const float* __restrict__ Wh, const float* __restrict__ bhp,
    u16* __restrict__ fT, u16* __restrict__ gT, u16* __restrict__ hhb)
{
  __shared__ float xs[CH][36];
  const int b  = blockIdx.x >> 7;
  const int n0 = (blockIdx.x & 127) * 32;
  const int t  = threadIdx.x;

  const float* xb = x + ((size_t)b * CH) * NPIX + n0;
  #pragma unroll
  for (int kk = 0; kk < 8; ++kk) {
    int v = kk * 256 + t;
    int c = v >> 3, p4 = v & 7;
    float4 d = *(const float4*)(xb + (size_t)c * NPIX + p4 * 4);
    *(float4*)&xs[c][p4 * 4] = d;
  }
  __syncthreads();

  const int o = t;
  float acch[32];
  #pragma unroll
  for (int p = 0; p < 32; ++p) acch[p] = bhp[o];

  const int o2 = t & 63;
  const int oo = o2 & 31;
  const bool isf = o2 < 32;
  const float* Wfg = isf ? Wf : Wg;
  const float bias2 = isf ? bfp[oo] : bgp[oo];
  const int pg = (t >> 6) * 8;
  float accf[8];
  #pragma unroll
  for (int p = 0; p < 8; ++p) accf[p] = bias2;

  const float* whr  = Wh  + o * CH;
  const float* wfgr = Wfg + oo * CH;
  for (int c = 0; c < CH; c += 4) {
    float4 wh4 = *(const float4*)(whr + c);
    float4 wf4 = *(const float4*)(wfgr + c);
    float wha[4] = {wh4.x, wh4.y, wh4.z, wh4.w};
    float wfa[4] = {wf4.x, wf4.y, wf4.z, wf4.w};
    #pragma unroll
    for (int cc = 0; cc < 4; ++cc) {
      float wh = wha[cc], wf = wfa[cc];
      #pragma unroll
      for (int p4 = 0; p4 < 8; ++p4) {
        float4 xv = *(const float4*)&xs[c + cc][p4 * 4];
        acch[p4*4+0] = fmaf(wh, xv.x, acch[p4*4+0]);
        acch[p4*4+1] = fmaf(wh, xv.y, acch[p4*4+1]);
        acch[p4*4+2] = fmaf(wh, xv.z, acch[p4*4+2]);
        acch[p4*4+3] = fmaf(wh, xv.w, acch[p4*4+3]);
      }
      #pragma unroll
      for (int p = 0; p < 8; ++p) accf[p] = fmaf(wf, xs[c + cc][pg + p], accf[p]);
    }
  }

  u16* hrow = hhb + ((size_t)b * CH + o) * NPIX + n0;
  #pragma unroll
  for (int q = 0; q < 4; ++q) {
    uint4 u;
    u.x = f2bf(acch[q*8+0]) | ((unsigned)f2bf(acch[q*8+1]) << 16);
    u.y = f2bf(acch[q*8+2]) | ((unsigned)f2bf(acch[q*8+3]) << 16);
    u.z = f2bf(acch[q*8+4]) | ((unsigned)f2bf(acch[q*8+5]) << 16);
    u.w = f2bf(acch[q*8+6]) | ((unsigned)f2bf(acch[q*8+7]) << 16);
    *(uint4*)(hrow + q * 8) = u;
  }
  u16* dst = (isf ? fT : gT) + ((size_t)b * NPIX + n0 + pg) * KD + oo;
  #pragma unroll
  for (int p = 0; p < 8; ++p) dst[(size_t)p * KD] = f2bf(accf[p]);
}

// ---------------------------------------------------------------------------
// Kernel 2 (fused attn + PV), 128-j chunks (T3 barrier amortization):
//  - 32 barriers/block (was 64); per wave per barrier: 4 QK + 32 PV MFMA.
//  - register discipline: s-tiles in pairs (8 regs), hh frags split
//    hcA (pre-barrier, 16) / hcB (issued post-barrier under MFMA cover),
//    g prefetch 16; live set across barrier ~90 -> fits (512,4) 128 cap.
//  - bf16 P^T tile [64][128] XOR-swizzled, double-buffered (2x16KB);
//    attention f32 re-expanded from it, co-op stored (issued BEFORE PV
//    MFMAs so nt-stores drain under compute), 512B-contiguous rows.
// ---------------------------------------------------------------------------
__global__ __launch_bounds__(512, 4) void fused_attn_pv(
    const u16* __restrict__ fT, const u16* __restrict__ gT,
    const u16* __restrict__ hhb, const float* __restrict__ x,
    const float* __restrict__ gamma,
    float* __restrict__ attn_out, float* __restrict__ outp)
{
  __shared__ u16 Pt[2][64 * 128];     // ping-pong bf16 P^T tiles, 16KB each
  __shared__ float part[8][64];
  __shared__ float invs[64];

  const int bid = blockIdx.x;
  const int b  = bid & 7;            // round-robin XCD: batch <-> XCD
  const int n0 = (bid >> 3) * 64;    // i-stripe base
  const int t  = threadIdx.x;
  const int iw = t >> 6, l = t & 63;
  const int lg = l >> 4, lm = l & 15;

  const u16* fb = fT + ((size_t)b * NPIX + n0) * KD;
  const u16* gb = gT + (size_t)b * NPIX * KD;
  const u16* hb = hhb + (size_t)b * CH * NPIX;

  f32x4 z4 = {0.f, 0.f, 0.f, 0.f};

  short8 ff[4];
  #pragma unroll
  for (int it = 0; it < 4; ++it)
    ff[it] = *(const short8*)(fb + (it * 16 + lm) * KD + lg * 8);

  // ---- pass 1: rowsums of exp(s) ----
  float sum[4][4];
  #pragma unroll
  for (int it = 0; it < 4; ++it)
    #pragma unroll
    for (int r = 0; r < 4; ++r) sum[it][r] = 0.f;

  const int j1 = iw * 512;
  for (int jt = 0; jt < 32; ++jt) {
    int j0 = j1 + jt * 16;
    short8 gf = *(const short8*)(gb + (size_t)(j0 + lm) * KD + lg * 8);
    #pragma unroll
    for (int it = 0; it < 4; ++it) {
      f32x4 s = __builtin_amdgcn_mfma_f32_16x16x32_bf16(ff[it], gf, z4, 0, 0, 0);
      #pragma unroll
      for (int r = 0; r < 4; ++r) sum[it][r] += __expf(s[r]);
    }
  }
  #pragma unroll
  for (int m = 1; m < 16; m <<= 1)
    #pragma unroll
    for (int it = 0; it < 4; ++it)
      #pragma unroll
      for (int r = 0; r < 4; ++r) sum[it][r] += __shfl_xor(sum[it][r], m, 64);
  if (lm == 0) {
    #pragma unroll
    for (int it = 0; it < 4; ++it)
      #pragma unroll
      for (int r = 0; r < 4; ++r) part[iw][it * 16 + lg * 4 + r] = sum[it][r];
  }
  __syncthreads();
  if (t < 64) {
    float s = 0.f;
    #pragma unroll
    for (int w2 = 0; w2 < 8; ++w2) s += part[w2][t];
    invs[t] = 1.0f / s;
  }
  __syncthreads();

  // ---- pass 2 ----
  const int it2 = iw >> 1, jsub = iw & 1;
  float inv4[4];
  #pragma unroll
  for (int r = 0; r < 4; ++r) inv4[r] = invs[it2 * 16 + lg * 4 + r];
  const short8 f2 = ff[it2];

  float* abase = attn_out + ((size_t)b * NPIX + n0) * NPIX;  // stripe base
  const int srow = t >> 3;             // co-op store: row 0..63
  const int sc   = (t & 7) * 16;       // col (elements), 16 floats/thread
  const int rb0 = srow * 256 + ((sc * 2) ^ ((srow & 7) << 4));
  const int rb1 = srow * 256 + (((sc + 8) * 2) ^ ((srow & 7) << 4));

  f32x4 acc[2][4];
  #pragma unroll
  for (int mf = 0; mf < 2; ++mf)
    #pragma unroll
    for (int nf = 0; nf < 4; ++nf) acc[mf][nf] = z4;

  short8 gP[4], gQ[4];

  auto LDG = [&](short8 (&g4)[4], int JC) {
    #pragma unroll
    for (int st = 0; st < 4; ++st)
      g4[st] = *(const short8*)(gb + (size_t)(JC + jsub * 64 + st * 16 + lm) * KD + lg * 8);
  };

  const u16* hrow0 = hb + (size_t)(iw * 32 + lm) * NPIX + lg * 8;
  const u16* hrow1 = hb + (size_t)(iw * 32 + 16 + lm) * NPIX + lg * 8;

  // one 128-j chunk.
  auto CHUNK = [&](u16* buf, short8 (&gc)[4], short8 (&gn)[4], int JC, int JN) {
    // QK + softmax in st-pairs (keeps s live-set at 8 regs)
    #pragma unroll
    for (int half = 0; half < 2; ++half) {
      f32x4 sA = __builtin_amdgcn_mfma_f32_16x16x32_bf16(f2, gc[half*2+0], z4, 0, 0, 0);
      f32x4 sB = __builtin_amdgcn_mfma_f32_16x16x32_bf16(f2, gc[half*2+1], z4, 0, 0, 0);
      if (half == 0) LDG(gn, JN);          // prefetch rides across barrier
      const int ibyte = (it2 * 16 + lg * 4) * 256;
      #pragma unroll
      for (int r = 0; r < 4; ++r) {
        float pA = __expf(sA[r]) * inv4[r];
        float pB = __expf(sB[r]) * inv4[r];
        int row = ibyte + r * 256;
        int sw  = ((lg * 4 + r) & 7) << 4;
        int jA  = (jsub * 64 + half * 32 + lm) * 2;
        *(u16*)((char*)buf + row + (jA ^ sw)) = f2bf(pA);
        *(u16*)((char*)buf + row + ((jA + 32) ^ sw)) = f2bf(pB);
      }
    }
    // hcA (ks=0,1) loaded pre-barrier
    short8 hA00 = *(const short8*)(hrow0 + JC);
    short8 hA10 = *(const short8*)(hrow1 + JC);
    short8 hA01 = *(const short8*)(hrow0 + JC + 32);
    short8 hA11 = *(const short8*)(hrow1 + JC + 32);
    asm volatile("s_waitcnt lgkmcnt(0)\n\ts_barrier" ::: "memory");
    // hcB (ks=2,3) issued now, consumed after ~16 MFMAs (L2 covered)
    short8 hB00 = *(const short8*)(hrow0 + JC + 64);
    short8 hB10 = *(const short8*)(hrow1 + JC + 64);
    short8 hB01 = *(const short8*)(hrow0 + JC + 96);
    short8 hB11 = *(const short8*)(hrow1 + JC + 96);
    // co-op attention store issued first: nt stores drain under PV MFMAs
    {
      short8 pw0 = *(const short8*)((char*)buf + rb0);
      short8 pw1 = *(const short8*)((char*)buf + rb1);
      f32x4 o0, o1, o2, o3;
      #pragma unroll
      for (int q = 0; q < 4; ++q) {
        o0[q] = bf2f((u16)pw0[q]);     o1[q] = bf2f((u16)pw0[q + 4]);
        o2[q] = bf2f((u16)pw1[q]);     o3[q] = bf2f((u16)pw1[q + 4]);
      }
      float* dst = abase + (size_t)srow * NPIX + JC + sc;
      __builtin_nontemporal_store(o0, (f32x4*)dst);
      __builtin_nontemporal_store(o1, (f32x4*)(dst + 4));
      __builtin_nontemporal_store(o2, (f32x4*)(dst + 8));
      __builtin_nontemporal_store(o3, (f32x4*)(dst + 12));
    }
    __builtin_amdgcn_s_setprio(1);
    #pragma unroll
    for (int ks = 0; ks < 2; ++ks) {
      #pragma unroll
      for (int nf = 0; nf < 4; ++nf) {
        int byte = (nf * 16 + lm) * 256 + (((ks * 64) + lg * 16) ^ ((lm & 7) << 4));
        short8 pfr = *(const short8*)((char*)buf + byte);
        acc[0][nf] = __builtin_amdgcn_mfma_f32_16x16x32_bf16(
            ks == 0 ? hA00 : hA01, pfr, acc[0][nf], 0, 0, 0);
        acc[1][nf] = __builtin_amdgcn_mfma_f32_16x16x32_bf16(
            ks == 0 ? hA10 : hA11, pfr, acc[1][nf], 0, 0, 0);
      }
    }
    #pragma unroll
    for (int ks = 0; ks < 2; ++ks) {
      #pragma unroll
      for (int nf = 0; nf < 4; ++nf) {
        int byte = (nf * 16 + lm) * 256 + (((128 + ks * 64) + lg * 16) ^ ((lm & 7) << 4));
        short8 pfr = *(const short8*)((char*)buf + byte);
        acc[0][nf] = __builtin_amdgcn_mfma_f32_16x16x32_bf16(
            ks == 0 ? hB00 : hB01, pfr, acc[0][nf], 0, 0, 0);
        acc[1][nf] = __builtin_amdgcn_mfma_f32_16x16x32_bf16(
            ks == 0 ? hB10 : hB11, pfr, acc[1][nf], 0, 0, 0);
      }
    }
    __builtin_amdgcn_s_setprio(0);
  };

  LDG(gP, 0);
  for (int jc = 0; jc < NPIX; jc += 256) {
    int n1 = (jc + 128) & (NPIX - 1);
    int n2 = (jc + 256) & (NPIX - 1);   // wraps to 0 on last iter (harmless)
    CHUNK(&Pt[0][0], gP, gQ, jc, n1);
    CHUNK(&Pt[1][0], gQ, gP, jc + 128, n2);
  }

  // ---- epilogue ----
  const float gm = gamma[0];
  #pragma unroll
  for (int mf = 0; mf < 2; ++mf) {
    #pragma unroll
    for (int r = 0; r < 4; ++r) {
      int c = iw * 32 + mf * 16 + lg * 4 + r;
      #pragma unroll
      for (int nf = 0; nf < 4; ++nf) {
        int i = n0 + nf * 16 + lm;
        size_t idx = ((size_t)b * CH + c) * NPIX + i;
        outp[idx] = fmaf(gm, acc[mf][nf][r], x[idx]);
      }
    }
  }
}

// ---------------------------------------------------------------------------
extern "C" void kernel_launch(void* const* d_in, const int* in_sizes, int n_in,
                              void* d_out, int out_size, void* d_ws, size_t ws_size,
                              hipStream_t stream) {
  const float* x     = (const float*)d_in[0];
  const float* Wf    = (const float*)d_in[1];
  const float* bf    = (const float*)d_in[2];
  const float* Wg    = (const float*)d_in[3];
  const float* bg    = (const float*)d_in[4];
  const float* Wh    = (const float*)d_in[5];
  const float* bh    = (const float*)d_in[6];
  const float* gamma = (const float*)d_in[7];

  float* outp = (float*)d_out;
  float* attn_out = outp + (size_t)BATCH * CH * NPIX;   // out | attention

  // ws: fT (2MB) | gT (2MB) | hh (16MB)
  u16* fT = (u16*)d_ws;
  u16* gT = fT + (size_t)BATCH * NPIX * KD;
  u16* hh = gT + (size_t)BATCH * NPIX * KD;

  proj_kernel<<<dim3(BATCH * (NPIX / 32)), dim3(256), 0, stream>>>(
      x, Wf, bf, Wg, bg, Wh, bh, fT, gT, hh);

  fused_attn_pv<<<dim3(BATCH * (NPIX / 64)), dim3(512), 0, stream>>>(
      fT, gT, hh, x, gamma, attn_out, outp);
}

// Round 11
// 381.684 us; speedup vs baseline: 1.8621x; 1.8621x over previous
//
#include <hip/hip_runtime.h>
#include <hip/hip_bf16.h>

typedef unsigned short u16;
typedef __attribute__((ext_vector_type(8))) short short8;  // 8 bf16 (4 VGPRs)
typedef __attribute__((ext_vector_type(4))) float f32x4;

#define BATCH 8
#define CH 256
#define NPIX 4096
#define KD 32   // C/8

static __device__ __forceinline__ u16 f2bf(float f) {
  union { __hip_bfloat16 h; u16 u; } cv;
  cv.h = __float2bfloat16(f);
  return cv.u;
}

// ---------------------------------------------------------------------------
// Kernel 1: projections. x [B][C][N] f32 -> fT/gT [B][N][32] bf16, hh [B][C][N] bf16
// ---------------------------------------------------------------------------
__global__ __launch_bounds__(256) void proj_kernel(
    const float* __restrict__ x,
    const float* __restrict__ Wf, const float* __restrict__ bfp,
    const float* __restrict__ Wg, const float* __restrict__ bgp,
    const float* __restrict__ Wh, const float* __restrict__ bhp,
    u16* __restrict__ fT, u16* __restrict__ gT, u16* __restrict__ hhb)
{
  __shared__ float xs[CH][36];
  const int b  = blockIdx.x >> 7;
  const int n0 = (blockIdx.x & 127) * 32;
  const int t  = threadIdx.x;

  const float* xb = x + ((size_t)b * CH) * NPIX + n0;
  #pragma unroll
  for (int kk = 0; kk < 8; ++kk) {
    int v = kk * 256 + t;
    int c = v >> 3, p4 = v & 7;
    float4 d = *(const float4*)(xb + (size_t)c * NPIX + p4 * 4);
    *(float4*)&xs[c][p4 * 4] = d;
  }
  __syncthreads();

  const int o = t;
  float acch[32];
  #pragma unroll
  for (int p = 0; p < 32; ++p) acch[p] = bhp[o];

  const int o2 = t & 63;
  const int oo = o2 & 31;
  const bool isf = o2 < 32;
  const float* Wfg = isf ? Wf : Wg;
  const float bias2 = isf ? bfp[oo] : bgp[oo];
  const int pg = (t >> 6) * 8;
  float accf[8];
  #pragma unroll
  for (int p = 0; p < 8; ++p) accf[p] = bias2;

  const float* whr  = Wh  + o * CH;
  const float* wfgr = Wfg + oo * CH;
  for (int c = 0; c < CH; c += 4) {
    float4 wh4 = *(const float4*)(whr + c);
    float4 wf4 = *(const float4*)(wfgr + c);
    float wha[4] = {wh4.x, wh4.y, wh4.z, wh4.w};
    float wfa[4] = {wf4.x, wf4.y, wf4.z, wf4.w};
    #pragma unroll
    for (int cc = 0; cc < 4; ++cc) {
      float wh = wha[cc], wf = wfa[cc];
      #pragma unroll
      for (int p4 = 0; p4 < 8; ++p4) {
        float4 xv = *(const float4*)&xs[c + cc][p4 * 4];
        acch[p4*4+0] = fmaf(wh, xv.x, acch[p4*4+0]);
        acch[p4*4+1] = fmaf(wh, xv.y, acch[p4*4+1]);
        acch[p4*4+2] = fmaf(wh, xv.z, acch[p4*4+2]);
        acch[p4*4+3] = fmaf(wh, xv.w, acch[p4*4+3]);
      }
      #pragma unroll
      for (int p = 0; p < 8; ++p) accf[p] = fmaf(wf, xs[c + cc][pg + p], accf[p]);
    }
  }

  u16* hrow = hhb + ((size_t)b * CH + o) * NPIX + n0;
  #pragma unroll
  for (int q = 0; q < 4; ++q) {
    uint4 u;
    u.x = f2bf(acch[q*8+0]) | ((unsigned)f2bf(acch[q*8+1]) << 16);
    u.y = f2bf(acch[q*8+2]) | ((unsigned)f2bf(acch[q*8+3]) << 16);
    u.z = f2bf(acch[q*8+4]) | ((unsigned)f2bf(acch[q*8+5]) << 16);
    u.w = f2bf(acch[q*8+6]) | ((unsigned)f2bf(acch[q*8+7]) << 16);
    *(uint4*)(hrow + q * 8) = u;
  }
  u16* dst = (isf ? fT : gT) + ((size_t)b * NPIX + n0 + pg) * KD + oo;
  #pragma unroll
  for (int p = 0; p < 8; ++p) dst[(size_t)p * KD] = f2bf(accf[p]);
}

// ---------------------------------------------------------------------------
// Kernel 2 (fused attn + PV), PRODUCER/CONSUMER wave specialization:
//  - waves 0-3 (producers): own 16 i-rows each; per 64-j chunk: QK MFMA,
//    softmax, nt attention store, bf16 P^T -> swizzled LDS. Live ~45 regs.
//  - waves 4-7 (consumers): own 64 c-rows each; PV only: acc[4][4] (64 AGPR)
//    + ~40 arch. pfr LDS reads hoisted over c-tiles -> 8 ds_read_b128/chunk.
//  - producers run ONE CHUNK AHEAD into ping-pong P^T tiles; one lgkm-only
//    barrier per half-chunk. No mixed live set -> no spills under (512,4)
//    (R10: VGPR=64 + 650MB scratch writes = the structural killer).
//  - setprio(1) around consumer MFMA cluster (T5 regime: role-split waves).
// ---------------------------------------------------------------------------
__global__ __launch_bounds__(512, 4) void fused_attn_pv(
    const u16* __restrict__ fT, const u16* __restrict__ gT,
    const u16* __restrict__ hhb, const float* __restrict__ x,
    const float* __restrict__ gamma,
    float* __restrict__ attn_out, float* __restrict__ outp)
{
  __shared__ u16 Pt[2][64 * 64];      // ping-pong bf16 P^T tiles, 8KB each
  __shared__ float part[8][64];
  __shared__ float invs[64];

  const int bid = blockIdx.x;
  const int b  = bid & 7;            // round-robin XCD: batch <-> XCD
  const int n0 = (bid >> 3) * 64;    // i-stripe base
  const int t  = threadIdx.x;
  const int iw = t >> 6, l = t & 63;
  const int lg = l >> 4, lm = l & 15;

  const u16* fb = fT + ((size_t)b * NPIX + n0) * KD;
  const u16* gb = gT + (size_t)b * NPIX * KD;
  const u16* hb = hhb + (size_t)b * CH * NPIX;

  f32x4 z4 = {0.f, 0.f, 0.f, 0.f};

  short8 ff[4];
  #pragma unroll
  for (int it = 0; it < 4; ++it)
    ff[it] = *(const short8*)(fb + (it * 16 + lm) * KD + lg * 8);

  // ---- pass 1: rowsums of exp(s) (all 8 waves) ----
  float sum[4][4];
  #pragma unroll
  for (int it = 0; it < 4; ++it)
    #pragma unroll
    for (int r = 0; r < 4; ++r) sum[it][r] = 0.f;

  const int j1 = iw * 512;
  for (int jt = 0; jt < 32; ++jt) {
    int j0 = j1 + jt * 16;
    short8 gf = *(const short8*)(gb + (size_t)(j0 + lm) * KD + lg * 8);
    #pragma unroll
    for (int it = 0; it < 4; ++it) {
      f32x4 s = __builtin_amdgcn_mfma_f32_16x16x32_bf16(ff[it], gf, z4, 0, 0, 0);
      #pragma unroll
      for (int r = 0; r < 4; ++r) sum[it][r] += __expf(s[r]);
    }
  }
  #pragma unroll
  for (int m = 1; m < 16; m <<= 1)
    #pragma unroll
    for (int it = 0; it < 4; ++it)
      #pragma unroll
      for (int r = 0; r < 4; ++r) sum[it][r] += __shfl_xor(sum[it][r], m, 64);
  if (lm == 0) {
    #pragma unroll
    for (int it = 0; it < 4; ++it)
      #pragma unroll
      for (int r = 0; r < 4; ++r) part[iw][it * 16 + lg * 4 + r] = sum[it][r];
  }
  __syncthreads();
  if (t < 64) {
    float s = 0.f;
    #pragma unroll
    for (int w2 = 0; w2 < 8; ++w2) s += part[w2][t];
    invs[t] = 1.0f / s;
  }
  __syncthreads();

  // ---- pass 2: producer/consumer ----
  const bool isprod = (iw < 4);
  const int pw = iw & 3;             // producer: i-tile; consumer: c-group

  // producer state
  float inv4[4];
  #pragma unroll
  for (int r = 0; r < 4; ++r) inv4[r] = invs[pw * 16 + lg * 4 + r];
  const short8 f2 = ff[pw];
  float* abase = attn_out + ((size_t)b * NPIX + n0 + pw * 16) * NPIX;

  // consumer state
  const u16* hbase = hb + (size_t)(pw * 64 + lm) * NPIX + lg * 8;

  f32x4 acc[4][4];
  if (!isprod) {
    #pragma unroll
    for (int a = 0; a < 4; ++a)
      #pragma unroll
      for (int c2 = 0; c2 < 4; ++c2) acc[a][c2] = z4;
  }

  auto PRODUCE = [&](u16* buf, int JC) {
    short8 g4[4];
    #pragma unroll
    for (int st = 0; st < 4; ++st)
      g4[st] = *(const short8*)(gb + (size_t)(JC + st * 16 + lm) * KD + lg * 8);
    #pragma unroll
    for (int st = 0; st < 4; ++st) {
      f32x4 s = __builtin_amdgcn_mfma_f32_16x16x32_bf16(f2, g4[st], z4, 0, 0, 0);
      #pragma unroll
      for (int r = 0; r < 4; ++r) {
        float p = __expf(s[r]) * inv4[r];
        __builtin_nontemporal_store(
            p, abase + (size_t)(lg * 4 + r) * NPIX + JC + st * 16 + lm);
        int iloc = pw * 16 + lg * 4 + r;
        int byte = iloc * 128 + (((st * 16 + lm) * 2) ^ ((iloc & 7) << 4));
        *(u16*)((char*)buf + byte) = f2bf(p);
      }
    }
  };

  auto CONSUME = [&](const u16* buf, int JC) {
    #pragma unroll
    for (int ks = 0; ks < 2; ++ks) {
      short8 h[4];
      #pragma unroll
      for (int ct = 0; ct < 4; ++ct)
        h[ct] = *(const short8*)(hbase + (size_t)(ct * 16) * NPIX + JC + ks * 32);
      __builtin_amdgcn_s_setprio(1);
      #pragma unroll
      for (int nf = 0; nf < 4; ++nf) {
        int byte = (nf * 16 + lm) * 128 + (((ks * 4 + lg) * 16) ^ ((lm & 7) << 4));
        short8 pfr = *(const short8*)((const char*)buf + byte);
        #pragma unroll
        for (int ct = 0; ct < 4; ++ct)
          acc[ct][nf] = __builtin_amdgcn_mfma_f32_16x16x32_bf16(
              h[ct], pfr, acc[ct][nf], 0, 0, 0);
      }
      __builtin_amdgcn_s_setprio(0);
    }
  };

  // prologue: producers fill tile 0 for chunk 0
  if (isprod) PRODUCE(&Pt[0][0], 0);
  __syncthreads();

  for (int jc = 0; jc < NPIX; jc += 128) {
    if (isprod) PRODUCE(&Pt[1][0], jc + 64);      // next chunk into other tile
    else        CONSUME(&Pt[0][0], jc);
    asm volatile("s_waitcnt lgkmcnt(0)\n\ts_barrier" ::: "memory");
    if (isprod) { if (jc + 128 < NPIX) PRODUCE(&Pt[0][0], jc + 128); }
    else        CONSUME(&Pt[1][0], jc + 64);
    asm volatile("s_waitcnt lgkmcnt(0)\n\ts_barrier" ::: "memory");
  }

  // ---- epilogue (consumers only) ----
  if (!isprod) {
    const float gm = gamma[0];
    #pragma unroll
    for (int ct = 0; ct < 4; ++ct) {
      #pragma unroll
      for (int r = 0; r < 4; ++r) {
        int c = pw * 64 + ct * 16 + lg * 4 + r;
        #pragma unroll
        for (int nf = 0; nf < 4; ++nf) {
          int i = n0 + nf * 16 + lm;
          size_t idx = ((size_t)b * CH + c) * NPIX + i;
          outp[idx] = fmaf(gm, acc[ct][nf][r], x[idx]);
        }
      }
    }
  }
}

// ---------------------------------------------------------------------------
extern "C" void kernel_launch(void* const* d_in, const int* in_sizes, int n_in,
                              void* d_out, int out_size, void* d_ws, size_t ws_size,
                              hipStream_t stream) {
  const float* x     = (const float*)d_in[0];
  const float* Wf    = (const float*)d_in[1];
  const float* bf    = (const float*)d_in[2];
  const float* Wg    = (const float*)d_in[3];
  const float* bg    = (const float*)d_in[4];
  const float* Wh    = (const float*)d_in[5];
  const float* bh    = (const float*)d_in[6];
  const float* gamma = (const float*)d_in[7];

  float* outp = (float*)d_out;
  float* attn_out = outp + (size_t)BATCH * CH * NPIX;   // out | attention

  // ws: fT (2MB) | gT (2MB) | hh (16MB)
  u16* fT = (u16*)d_ws;
  u16* gT = fT + (size_t)BATCH * NPIX * KD;
  u16* hh = gT + (size_t)BATCH * NPIX * KD;

  proj_kernel<<<dim3(BATCH * (NPIX / 32)), dim3(256), 0, stream>>>(
      x, Wf, bf, Wg, bg, Wh, bh, fT, gT, hh);

  fused_attn_pv<<<dim3(BATCH * (NPIX / 64)), dim3(512), 0, stream>>>(
      fT, gT, hh, x, gamma, attn_out, outp);
}

// Round 12
// 328.027 us; speedup vs baseline: 2.1667x; 1.1636x over previous
//
#include <hip/hip_runtime.h>
#include <hip/hip_bf16.h>

typedef unsigned short u16;
typedef __attribute__((ext_vector_type(8))) short short8;  // 8 bf16 (4 VGPRs)
typedef __attribute__((ext_vector_type(4))) float f32x4;

#define BATCH 8
#define CH 256
#define NPIX 4096
#define KD 32   // C/8

static __device__ __forceinline__ u16 f2bf(float f) {
  union { __hip_bfloat16 h; u16 u; } cv;
  cv.h = __float2bfloat16(f);
  return cv.u;
}

// ---------------------------------------------------------------------------
// Kernel 1: projections. x [B][C][N] f32 -> fT/gT [B][N][32] bf16, hh [B][C][N] bf16
// ---------------------------------------------------------------------------
__global__ __launch_bounds__(256) void proj_kernel(
    const float* __restrict__ x,
    const float* __restrict__ Wf, const float* __restrict__ bfp,
    const float* __restrict__ Wg, const float* __restrict__ bgp,
    const float* __restrict__ Wh, const float* __restrict__ bhp,
    u16* __restrict__ fT, u16* __restrict__ gT, u16* __restrict__ hhb)
{
  __shared__ float xs[CH][36];
  const int b  = blockIdx.x >> 7;
  const int n0 = (blockIdx.x & 127) * 32;
  const int t  = threadIdx.x;

  const float* xb = x + ((size_t)b * CH) * NPIX + n0;
  #pragma unroll
  for (int kk = 0; kk < 8; ++kk) {
    int v = kk * 256 + t;
    int c = v >> 3, p4 = v & 7;
    float4 d = *(const float4*)(xb + (size_t)c * NPIX + p4 * 4);
    *(float4*)&xs[c][p4 * 4] = d;
  }
  __syncthreads();

  const int o = t;
  float acch[32];
  #pragma unroll
  for (int p = 0; p < 32; ++p) acch[p] = bhp[o];

  const int o2 = t & 63;
  const int oo = o2 & 31;
  const bool isf = o2 < 32;
  const float* Wfg = isf ? Wf : Wg;
  const float bias2 = isf ? bfp[oo] : bgp[oo];
  const int pg = (t >> 6) * 8;
  float accf[8];
  #pragma unroll
  for (int p = 0; p < 8; ++p) accf[p] = bias2;

  const float* whr  = Wh  + o * CH;
  const float* wfgr = Wfg + oo * CH;
  for (int c = 0; c < CH; c += 4) {
    float4 wh4 = *(const float4*)(whr + c);
    float4 wf4 = *(const float4*)(wfgr + c);
    float wha[4] = {wh4.x, wh4.y, wh4.z, wh4.w};
    float wfa[4] = {wf4.x, wf4.y, wf4.z, wf4.w};
    #pragma unroll
    for (int cc = 0; cc < 4; ++cc) {
      float wh = wha[cc], wf = wfa[cc];
      #pragma unroll
      for (int p4 = 0; p4 < 8; ++p4) {
        float4 xv = *(const float4*)&xs[c + cc][p4 * 4];
        acch[p4*4+0] = fmaf(wh, xv.x, acch[p4*4+0]);
        acch[p4*4+1] = fmaf(wh, xv.y, acch[p4*4+1]);
        acch[p4*4+2] = fmaf(wh, xv.z, acch[p4*4+2]);
        acch[p4*4+3] = fmaf(wh, xv.w, acch[p4*4+3]);
      }
      #pragma unroll
      for (int p = 0; p < 8; ++p) accf[p] = fmaf(wf, xs[c + cc][pg + p], accf[p]);
    }
  }

  u16* hrow = hhb + ((size_t)b * CH + o) * NPIX + n0;
  #pragma unroll
  for (int q = 0; q < 4; ++q) {
    uint4 u;
    u.x = f2bf(acch[q*8+0]) | ((unsigned)f2bf(acch[q*8+1]) << 16);
    u.y = f2bf(acch[q*8+2]) | ((unsigned)f2bf(acch[q*8+3]) << 16);
    u.z = f2bf(acch[q*8+4]) | ((unsigned)f2bf(acch[q*8+5]) << 16);
    u.w = f2bf(acch[q*8+6]) | ((unsigned)f2bf(acch[q*8+7]) << 16);
    *(uint4*)(hrow + q * 8) = u;
  }
  u16* dst = (isf ? fT : gT) + ((size_t)b * NPIX + n0 + pg) * KD + oo;
  #pragma unroll
  for (int p = 0; p < 8; ++p) dst[(size_t)p * KD] = f2bf(accf[p]);
}

// ---------------------------------------------------------------------------
// Kernel 2 (fused attn + PV): R5 champion structure + register diet at
// constant occupancy. Single variable vs champion: hh frags loaded in-chunk
// (L2-resident, XCD-pinned) instead of 32 cross-chunk prefetch regs; live
// set ~113 <= 128-cap of (512,4) -> no main-loop spills AND 2 blocks/CU.
//  - 64-j chunks, g(t+1) prefetch rides vmcnt across the lgkm-only barrier.
//  - attention f32 stores non-temporal (scattered 64B — proven faster than
//    co-op path in R9).
// ---------------------------------------------------------------------------
__global__ __launch_bounds__(512, 4) void fused_attn_pv(
    const u16* __restrict__ fT, const u16* __restrict__ gT,
    const u16* __restrict__ hhb, const float* __restrict__ x,
    const float* __restrict__ gamma,
    float* __restrict__ attn_out, float* __restrict__ outp)
{
  __shared__ u16 Pt[2][64 * 64];    // ping-pong P^T tiles, 8KB each
  __shared__ float part[8][64];
  __shared__ float invs[64];

  const int bid = blockIdx.x;
  const int b  = bid & 7;            // round-robin XCD: batch <-> XCD
  const int n0 = (bid >> 3) * 64;    // i-stripe base
  const int t  = threadIdx.x;
  const int iw = t >> 6, l = t & 63;
  const int lg = l >> 4, lm = l & 15;

  const u16* fb = fT + ((size_t)b * NPIX + n0) * KD;
  const u16* gb = gT + (size_t)b * NPIX * KD;
  const u16* hb = hhb + (size_t)b * CH * NPIX;

  f32x4 z4 = {0.f, 0.f, 0.f, 0.f};

  short8 ff[4];
  #pragma unroll
  for (int it = 0; it < 4; ++it)
    ff[it] = *(const short8*)(fb + (it * 16 + lm) * KD + lg * 8);

  // ---- pass 1: rowsums of exp(s) ----
  float sum[4][4];
  #pragma unroll
  for (int it = 0; it < 4; ++it)
    #pragma unroll
    for (int r = 0; r < 4; ++r) sum[it][r] = 0.f;

  const int j1 = iw * 512;
  for (int jt = 0; jt < 32; ++jt) {
    int j0 = j1 + jt * 16;
    short8 gf = *(const short8*)(gb + (size_t)(j0 + lm) * KD + lg * 8);
    #pragma unroll
    for (int it = 0; it < 4; ++it) {
      f32x4 s = __builtin_amdgcn_mfma_f32_16x16x32_bf16(ff[it], gf, z4, 0, 0, 0);
      #pragma unroll
      for (int r = 0; r < 4; ++r) sum[it][r] += __expf(s[r]);
    }
  }
  #pragma unroll
  for (int m = 1; m < 16; m <<= 1)
    #pragma unroll
    for (int it = 0; it < 4; ++it)
      #pragma unroll
      for (int r = 0; r < 4; ++r) sum[it][r] += __shfl_xor(sum[it][r], m, 64);
  if (lm == 0) {
    #pragma unroll
    for (int it = 0; it < 4; ++it)
      #pragma unroll
      for (int r = 0; r < 4; ++r) part[iw][it * 16 + lg * 4 + r] = sum[it][r];
  }
  __syncthreads();
  if (t < 64) {
    float s = 0.f;
    #pragma unroll
    for (int w2 = 0; w2 < 8; ++w2) s += part[w2][t];
    invs[t] = 1.0f / s;
  }
  __syncthreads();

  // ---- pass 2 ----
  const int it2 = iw >> 1, jsub = iw & 1;
  float inv4[4];
  #pragma unroll
  for (int r = 0; r < 4; ++r) inv4[r] = invs[it2 * 16 + lg * 4 + r];
  const short8 f2 = ff[it2];

  float* arow = attn_out + ((size_t)b * NPIX + n0 + it2 * 16 + lg * 4) * NPIX;

  f32x4 acc[2][4];
  #pragma unroll
  for (int mf = 0; mf < 2; ++mf)
    #pragma unroll
    for (int nf = 0; nf < 4; ++nf) acc[mf][nf] = z4;

  short8 gP[2], gQ[2];

  auto LDG = [&](short8 (&g2)[2], int JC) {
    #pragma unroll
    for (int st = 0; st < 2; ++st)
      g2[st] = *(const short8*)(gb + (size_t)(JC + jsub * 32 + st * 16 + lm) * KD + lg * 8);
  };

  // one 64-j chunk: QK with gc, prefetch gn@JN, load hh frags (L2-hot),
  // softmax+stores, barrier (lgkm only), PV.
  auto HALF = [&](u16* buf, short8 (&gc)[2], short8 (&gn)[2], int JC, int JN) {
    f32x4 s[2];
    #pragma unroll
    for (int st = 0; st < 2; ++st)
      s[st] = __builtin_amdgcn_mfma_f32_16x16x32_bf16(f2, gc[st], z4, 0, 0, 0);
    LDG(gn, JN);                           // in flight across the barrier
    short8 hc[2][2];
    #pragma unroll
    for (int m = 0; m < 2; ++m)
      #pragma unroll
      for (int ks = 0; ks < 2; ++ks)
        hc[m][ks] = *(const short8*)(hb + (size_t)(iw * 32 + m * 16 + lm) * NPIX
                                     + JC + ks * 32 + lg * 8);
    #pragma unroll
    for (int st = 0; st < 2; ++st) {
      const int j0 = JC + jsub * 32 + st * 16;
      #pragma unroll
      for (int r = 0; r < 4; ++r) {
        float p = __expf(s[st][r]) * inv4[r];
        __builtin_nontemporal_store(p, arow + (size_t)r * NPIX + j0 + lm);
        int iloc = it2 * 16 + lg * 4 + r;
        int jloc = jsub * 32 + st * 16 + lm;
        int byte = iloc * 128 + ((jloc * 2) ^ (((lg * 4 + r) & 7) << 4));
        *(u16*)((char*)buf + byte) = f2bf(p);
      }
    }
    asm volatile("s_waitcnt lgkmcnt(0)\n\ts_barrier" ::: "memory");
    #pragma unroll
    for (int nf = 0; nf < 4; ++nf) {
      #pragma unroll
      for (int ks = 0; ks < 2; ++ks) {
        int byte = (nf * 16 + lm) * 128 + (((ks * 4 + lg) * 16) ^ ((lm & 7) << 4));
        short8 pf = *(const short8*)((char*)buf + byte);
        acc[0][nf] = __builtin_amdgcn_mfma_f32_16x16x32_bf16(hc[0][ks], pf, acc[0][nf], 0, 0, 0);
        acc[1][nf] = __builtin_amdgcn_mfma_f32_16x16x32_bf16(hc[1][ks], pf, acc[1][nf], 0, 0, 0);
      }
    }
  };

  LDG(gP, 0);
  for (int jc = 0; jc < NPIX; jc += 128) {
    int n1 = (jc + 64) & (NPIX - 1);
    int n2 = (jc + 128) & (NPIX - 1);   // wraps to 0 on last iter (harmless)
    HALF(&Pt[0][0], gP, gQ, jc, n1);
    HALF(&Pt[1][0], gQ, gP, jc + 64, n2);
  }

  // ---- epilogue ----
  const float gm = gamma[0];
  #pragma unroll
  for (int mf = 0; mf < 2; ++mf) {
    #pragma unroll
    for (int r = 0; r < 4; ++r) {
      int c = iw * 32 + mf * 16 + lg * 4 + r;
      #pragma unroll
      for (int nf = 0; nf < 4; ++nf) {
        int i = n0 + nf * 16 + lm;
        size_t idx = ((size_t)b * CH + c) * NPIX + i;
        outp[idx] = fmaf(gm, acc[mf][nf][r], x[idx]);
      }
    }
  }
}

// ---------------------------------------------------------------------------
extern "C" void kernel_launch(void* const* d_in, const int* in_sizes, int n_in,
                              void* d_out, int out_size, void* d_ws, size_t ws_size,
                              hipStream_t stream) {
  const float* x     = (const float*)d_in[0];
  const float* Wf    = (const float*)d_in[1];
  const float* bf    = (const float*)d_in[2];
  const float* Wg    = (const float*)d_in[3];
  const float* bg    = (const float*)d_in[4];
  const float* Wh    = (const float*)d_in[5];
  const float* bh    = (const float*)d_in[6];
  const float* gamma = (const float*)d_in[7];

  float* outp = (float*)d_out;
  float* attn_out = outp + (size_t)BATCH * CH * NPIX;   // out | attention

  // ws: fT (2MB) | gT (2MB) | hh (16MB)
  u16* fT = (u16*)d_ws;
  u16* gT = fT + (size_t)BATCH * NPIX * KD;
  u16* hh = gT + (size_t)BATCH * NPIX * KD;

  proj_kernel<<<dim3(BATCH * (NPIX / 32)), dim3(256), 0, stream>>>(
      x, Wf, bf, Wg, bg, Wh, bh, fT, gT, hh);

  fused_attn_pv<<<dim3(BATCH * (NPIX / 64)), dim3(512), 0, stream>>>(
      fT, gT, hh, x, gamma, attn_out, outp);
}